// Round 15
// baseline (204.574 us; speedup 1.0000x reference)
//
#include <hip/hip_runtime.h>

#define NB_HG 2048   // H*G = 32*64
#define DIM_N 128
#define DIM_D 128
#define DIM_S 256
#define PH 16        // staged rows per phase (ping-pong: 2 buffers)
#define BSW 128      // staged B width = block's s-window

// Numerics: golden = per-element strictly sequential ascending-d fp32 FMA over
// the SELECTED d's only (masked-out terms exact zeros). Verified bit-exact
// rounds 4-14. Compaction + phase split preserve chain order; X/B bits pass
// through LDS unmodified.
// LDS swizzle pos = idx ^ (4*(row&7)) — SQ_LDS_BANK_CONFLICT=0 verified r5-14.
// R13/R14 post-mortem: reg-staged prefetch spills (allocator won't hold
// in-flight regs across the 64-acc COMPUTE; WRITE_SIZE 192-259 MB).
// This round: global_load_lds DMA (no VGPR round-trip, nothing to spill).
// Swizzle achieved by pre-swizzling the per-lane GLOBAL source address
// (LDS dest is wave-uniform base + lane*size, linear).

typedef const __attribute__((address_space(1))) void* gas_t;
typedef __attribute__((address_space(3))) void* las_t;

__device__ __forceinline__ void dma4(const float* g, float* l) {
    __builtin_amdgcn_global_load_lds((gas_t)g, (las_t)l, 4, 0, 0);
}
__device__ __forceinline__ void dma16(const float* g, float* l) {
    __builtin_amdgcn_global_load_lds((gas_t)g, (las_t)l, 16, 0, 0);
}

__global__ void transpose_proj_kernel(const float* __restrict__ proj,
                                      float* __restrict__ projT)
{
    const int d = blockIdx.x;                      // 128
    const int s = threadIdx.x;                     // 256
    projT[d * DIM_S + s] = proj[s * DIM_D + d];    // coalesced write
}

template<bool TP>
__global__ __launch_bounds__(256)
void qjl_sketch_kernel(const float* __restrict__ data,
                       const float* __restrict__ mask,
                       const float* __restrict__ pmat,   // TP ? projT[d][s] : proj[s][d]
                       int* __restrict__ out)
{
    __shared__ float Xt[2][PH * DIM_N];            // 2 x 8 KB
    __shared__ float Bs[2][PH * BSW];              // 2 x 8 KB
    __shared__ int   cidx[DIM_D];
    __shared__ int   wcnt[2];

    const int type = blockIdx.x;   // 0: inlier s<128, 1: inlier s>=128, 2: outlier s<128
    const int hg   = blockIdx.y;
    const int tid  = threadIdx.x;

    // ---------- build compacted ascending list of selected d's ----------
    bool sel = false; int pos = 0, w = 0;
    if (tid < 128) {                               // waves 0,1 only (whole waves)
        const float m = mask[hg * DIM_D + tid];    // exactly 0.0f or 1.0f
        sel = (type == 2) ? (m != 0.0f) : (m == 0.0f);
        const unsigned long long bal = __ballot(sel);
        const int lane = tid & 63;
        w = tid >> 6;
        if (lane == 0) wcnt[w] = __popcll(bal);
        pos = __popcll(bal & ((1ull << lane) - 1ull));
    }
    __syncthreads();
    if (sel) cidx[pos + (w ? wcnt[0] : 0)] = tid;  // tid == d, ascending preserved
    __syncthreads();
    const int K = wcnt[0] + wcnt[1];               // uniform across block

    const int tn = tid & 15;                       // 16 n-groups
    const int ts = tid >> 4;                       // 16 s-groups
    const int C0 = 4 * tn;
    const int sl = ts * 8;                         // s_local base
    const int sbase = (type == 1) ? 128 : 0;

    float acc[8][8];                               // [j: s-bit][i: n-slot]
    #pragma unroll
    for (int j = 0; j < 8; ++j)
        #pragma unroll
        for (int i = 0; i < 8; ++i) acc[j][i] = 0.0f;

    const int l  = tid & 63;                       // lane
    const int wv = tid >> 6;                       // wave 0..3
    const float* Xg = data + (size_t)hg * (DIM_N * DIM_D);

    // async-DMA stage of PH rows into buffer bb (index-clamped padding;
    // rows cl >= kp hold garbage and are never read)
    auto ISSUE = [&](int base, int bb) {
        #pragma unroll
        for (int r = 0; r < 4; ++r) {              // X: 4 rows/wave, 2 halves, 4B DMA
            const int cl  = wv * 4 + r;
            const int src = base + cl;
            const int dg  = cidx[src < K ? src : K - 1];
            const int pcs = 4 * (cl & 7);
            #pragma unroll
            for (int h = 0; h < 2; ++h) {
                const int n = h * 64 + (l ^ pcs);  // pre-swizzled source
                dma4(Xg + (size_t)n * DIM_D + dg, &Xt[bb][cl * DIM_N + h * 64]);
            }
        }
        if (TP) {
            #pragma unroll
            for (int rr = 0; rr < 2; ++rr) {       // B: 2 rows per 16B DMA
                const int cl0  = wv * 4 + rr * 2;
                const int row  = cl0 + (l >> 5);
                const int src  = base + row;
                const int dg   = cidx[src < K ? src : K - 1];
                const int pcsr = 4 * (row & 7);
                const int c4   = 4 * (l & 31);     // stored chunk; fetch (c4^pcsr)
                dma16(pmat + (size_t)dg * DIM_S + sbase + (c4 ^ pcsr),
                      &Bs[bb][cl0 * BSW]);
            }
        } else {
            #pragma unroll
            for (int r = 0; r < 4; ++r) {          // B gather fallback, 4B DMA
                const int cl  = wv * 4 + r;
                const int src = base + cl;
                const int dg  = cidx[src < K ? src : K - 1];
                const int pcs = 4 * (cl & 7);
                #pragma unroll
                for (int h = 0; h < 2; ++h) {
                    const int s_l = h * 64 + (l ^ pcs);
                    dma4(pmat + (size_t)(sbase + s_l) * DIM_D + dg,
                         &Bs[bb][cl * BSW + h * 64]);
                }
            }
        }
    };

    auto COMPUTE = [&](int bb, int kp) {
        const float* Xb = Xt[bb];
        const float* Bb = Bs[bb];
        #pragma unroll 8
        for (int cl = 0; cl < kp; ++cl) {          // ascending selected d
            const int pcs = 4 * (cl & 7);          // compile-time under unroll
            const int pA  = sl ^ pcs;              // holds s_local sl..sl+3
            const float4 bA = *reinterpret_cast<const float4*>(&Bb[cl * BSW + pA]);
            const float4 bB = *reinterpret_cast<const float4*>(&Bb[cl * BSW + (pA ^ 4)]);
            const int P = C0 ^ pcs;
            const float4 q0 = *reinterpret_cast<const float4*>(&Xb[cl * DIM_N + P]);
            const float4 q1 = *reinterpret_cast<const float4*>(&Xb[cl * DIM_N + P + 64]);

            #pragma unroll
            for (int j = 0; j < 8; ++j) {
                const float bv = (j == 0) ? bA.x : (j == 1) ? bA.y : (j == 2) ? bA.z
                               : (j == 3) ? bA.w : (j == 4) ? bB.x : (j == 5) ? bB.y
                               : (j == 6) ? bB.z : bB.w;
                acc[j][0] = fmaf(bv, q0.x, acc[j][0]);   // serial dep: order fixed
                acc[j][1] = fmaf(bv, q0.y, acc[j][1]);
                acc[j][2] = fmaf(bv, q0.z, acc[j][2]);
                acc[j][3] = fmaf(bv, q0.w, acc[j][3]);
                acc[j][4] = fmaf(bv, q1.x, acc[j][4]);
                acc[j][5] = fmaf(bv, q1.y, acc[j][5]);
                acc[j][6] = fmaf(bv, q1.z, acc[j][6]);
                acc[j][7] = fmaf(bv, q1.w, acc[j][7]);
            }
        }
    };

    // prologue: DMA phase 0 into buffer 0; syncthreads drains vmcnt(0)
    ISSUE(0, 0);
    __syncthreads();

    int b = 0;
    for (int base = 0; base < K; base += PH, b ^= 1) {
        const int kpc  = (K - base < PH) ? (K - base) : PH;
        const bool nxt = (base + PH < K);
        if (nxt) ISSUE(base + PH, b ^ 1);          // async DMA under compute
        COMPUTE(b, kpc);                           // pure LDS + FMA
        if (nxt) __syncthreads();                  // vmcnt(0)+barrier: next phase ready
    }

    // ---------- sign-pack (bit j = sbase+sl+j > 0) and store as int32 ----------
    const size_t inl_total = (size_t)NB_HG * DIM_N * 32;   // 8388608
    #pragma unroll
    for (int i = 0; i < 8; ++i) {
        int byte = 0;
        #pragma unroll
        for (int j = 0; j < 8; ++j)
            if (acc[j][i] > 0.0f) byte |= (1 << j);
        const int n = (i < 4) ? (C0 + i) : (64 + C0 + (i - 4));
        size_t idx;
        if (type == 2)
            idx = inl_total + ((size_t)hg * DIM_N + n) * 16 + ts;
        else
            idx = ((size_t)hg * DIM_N + n) * 32 + (type == 1 ? 16 : 0) + ts;
        out[idx] = byte;
    }
}

extern "C" void kernel_launch(void* const* d_in, const int* in_sizes, int n_in,
                              void* d_out, int out_size, void* d_ws, size_t ws_size,
                              hipStream_t stream) {
    const float* data = (const float*)d_in[0];   // (1,32,64,128,128) fp32
    const float* mask = (const float*)d_in[1];   // (1,32,64,128) fp32, values {0,1}
    const float* proj = (const float*)d_in[2];   // (256,128) fp32
    int* out = (int*)d_out;                      // 8388608 inlier + 4194304 outlier int32

    dim3 grid(3, NB_HG);
    const size_t tp_bytes = (size_t)DIM_D * DIM_S * sizeof(float);   // 128 KB
    if (ws_size >= tp_bytes) {
        float* projT = (float*)d_ws;
        transpose_proj_kernel<<<DIM_D, DIM_S, 0, stream>>>(proj, projT);
        qjl_sketch_kernel<true><<<grid, 256, 0, stream>>>(data, mask, projT, out);
    } else {
        qjl_sketch_kernel<false><<<grid, 256, 0, stream>>>(data, mask, proj, out);
    }
}

// Round 16
// 191.344 us; speedup vs baseline: 1.0691x; 1.0691x over previous
//
#include <hip/hip_runtime.h>

#define NB_HG 2048   // H*G = 32*64
#define DIM_N 128
#define DIM_D 128
#define DIM_S 256

// Numerics: golden = per-element strictly sequential ascending-d fp32 FMA over
// the SELECTED d's only (masked-out terms exact zeros; fmaf(b,±0,acc)==acc).
// Verified bit-exact rounds 4-15. Merged-type block: one block per hg stages
// the FULL X tile once (inlier ∪ outlier = all 128 d), then three compacted
// passes (inlier s<128, inlier s>=128, outlier s<128). Chain order per output
// is unchanged: ascending selected d.
// LDS: Xt[d][n ^ 4*(d&7)] float4-XOR swizzle — SQ_LDS_BANK_CONFLICT=0
// verified rounds 5-15 (reads here use runtime d -> swizzle computed per iter).

__global__ void transpose_proj_kernel(const float* __restrict__ proj,
                                      float* __restrict__ projT)
{
    const int d = blockIdx.x;                      // 128
    const int s = threadIdx.x;                     // 256
    projT[d * DIM_S + s] = proj[s * DIM_D + d];    // coalesced write
}

template<bool TP>
__global__ __launch_bounds__(256)
void qjl_sketch_kernel(const float* __restrict__ data,
                       const float* __restrict__ mask,
                       const float* __restrict__ pmat,   // TP ? projT[d][s] : proj[s][d]
                       int* __restrict__ out)
{
    __shared__ float Xt[DIM_D * DIM_N];            // 64 KB: full X tile, swizzled
    __shared__ int   din[DIM_D];                   // inlier d's, ascending
    __shared__ int   dout[DIM_D];                  // outlier d's, ascending
    __shared__ int   win[2];                       // per-wave inlier counts

    const int hg  = blockIdx.x;
    const int tid = threadIdx.x;

    // ---------- build both compacted ascending d-lists ----------
    const int  lane = tid & 63;
    const int  w    = tid >> 6;
    bool is_in = false; int rank_in = 0;
    if (tid < 128) {                               // waves 0,1 only (whole waves)
        const float m = mask[hg * DIM_D + tid];    // exactly 0.0f or 1.0f
        is_in = (m == 0.0f);
        const unsigned long long bal = __ballot(is_in);
        if (lane == 0) win[w] = __popcll(bal);
        rank_in = __popcll(bal & ((1ull << lane) - 1ull));
    }
    __syncthreads();
    const int Kin = win[0] + win[1];               // uniform across block
    if (tid < 128) {
        if (is_in) din [rank_in          + (w ? win[0]        : 0)] = tid;
        else       dout[(lane - rank_in) + (w ? (64 - win[0]) : 0)] = tid;
    }

    // ---------- stage FULL X tile, transposed + swizzled (no mask mult) ----------
    {
        const int d  = tid & 127;
        const int nh = tid >> 7;                   // 0 or 1
        const float* Xs = data + (size_t)hg * (DIM_N * DIM_D) + d;
        const int pcs = 4 * (d & 7);
        float* row = &Xt[d * DIM_N];
        #pragma unroll
        for (int g = 0; g < 16; ++g) {
            const int n0 = g * 8 + nh * 4;         // 4-aligned logical n block
            float4 v;
            v.x = Xs[(size_t)(n0 + 0) * DIM_D];    // coalesced: lanes span d
            v.y = Xs[(size_t)(n0 + 1) * DIM_D];
            v.z = Xs[(size_t)(n0 + 2) * DIM_D];
            v.w = Xs[(size_t)(n0 + 3) * DIM_D];
            *reinterpret_cast<float4*>(&row[n0 ^ pcs]) = v;
        }
    }
    __syncthreads();                               // lists + tile ready; last barrier

    // ---------- three register-tiled passes over compacted lists ----------
    const int tn = tid & 15;                       // 16 n-groups
    const int ts = tid >> 4;                       // 16 s-groups
    const int C0 = 4 * tn;
    const int sl = ts * 8;                         // s offset within 128-window
    const size_t inl_total = (size_t)NB_HG * DIM_N * 32;   // 8388608

    auto PASS = [&](const int* __restrict__ list, int cnt, int sbase, int typ) {
        float acc[8][8];                           // [j: s-bit][i: n-slot]
        #pragma unroll
        for (int j = 0; j < 8; ++j)
            #pragma unroll
            for (int i = 0; i < 8; ++i) acc[j][i] = 0.0f;

        #pragma unroll 4
        for (int ci = 0; ci < cnt; ++ci) {         // ascending selected d
            const int dl = list[ci];               // uniform LDS broadcast
            float4 b0, b1;
            if (TP) {
                const float* pr = pmat + (size_t)dl * DIM_S + sbase + sl;
                b0 = *reinterpret_cast<const float4*>(pr);       // L2-hot projT
                b1 = *reinterpret_cast<const float4*>(pr + 4);
            } else {
                b0.x = pmat[(size_t)(sbase + sl + 0) * DIM_D + dl];
                b0.y = pmat[(size_t)(sbase + sl + 1) * DIM_D + dl];
                b0.z = pmat[(size_t)(sbase + sl + 2) * DIM_D + dl];
                b0.w = pmat[(size_t)(sbase + sl + 3) * DIM_D + dl];
                b1.x = pmat[(size_t)(sbase + sl + 4) * DIM_D + dl];
                b1.y = pmat[(size_t)(sbase + sl + 5) * DIM_D + dl];
                b1.z = pmat[(size_t)(sbase + sl + 6) * DIM_D + dl];
                b1.w = pmat[(size_t)(sbase + sl + 7) * DIM_D + dl];
            }
            const int pcs = 4 * (dl & 7);          // runtime swizzle (few VALU)
            const int P   = C0 ^ pcs;
            const float* r = &Xt[dl * DIM_N + P];
            const float4 q0 = *reinterpret_cast<const float4*>(r);        // n=C0..+3
            const float4 q1 = *reinterpret_cast<const float4*>(r + 64);   // n=64+C0..
            const float bv[8] = {b0.x, b0.y, b0.z, b0.w, b1.x, b1.y, b1.z, b1.w};

            #pragma unroll
            for (int j = 0; j < 8; ++j) {
                acc[j][0] = fmaf(bv[j], q0.x, acc[j][0]);   // serial dep: order fixed
                acc[j][1] = fmaf(bv[j], q0.y, acc[j][1]);
                acc[j][2] = fmaf(bv[j], q0.z, acc[j][2]);
                acc[j][3] = fmaf(bv[j], q0.w, acc[j][3]);
                acc[j][4] = fmaf(bv[j], q1.x, acc[j][4]);
                acc[j][5] = fmaf(bv[j], q1.y, acc[j][5]);
                acc[j][6] = fmaf(bv[j], q1.z, acc[j][6]);
                acc[j][7] = fmaf(bv[j], q1.w, acc[j][7]);
            }
        }

        // sign-pack (bit j = sbase+sl+j > 0) and store as int32
        #pragma unroll
        for (int i = 0; i < 8; ++i) {
            int byte = 0;
            #pragma unroll
            for (int j = 0; j < 8; ++j)
                if (acc[j][i] > 0.0f) byte |= (1 << j);
            const int n = (i < 4) ? (C0 + i) : (64 + C0 + (i - 4));
            size_t idx;
            if (typ == 2)
                idx = inl_total + ((size_t)hg * DIM_N + n) * 16 + ts;
            else
                idx = ((size_t)hg * DIM_N + n) * 32 + (typ == 1 ? 16 : 0) + ts;
            out[idx] = byte;
        }
    };

    PASS(din,  Kin,         0,   0);               // inlier, s 0..127
    PASS(din,  Kin,         128, 1);               // inlier, s 128..255
    PASS(dout, DIM_D - Kin, 0,   2);               // outlier, s 0..127

}

extern "C" void kernel_launch(void* const* d_in, const int* in_sizes, int n_in,
                              void* d_out, int out_size, void* d_ws, size_t ws_size,
                              hipStream_t stream) {
    const float* data = (const float*)d_in[0];   // (1,32,64,128,128) fp32
    const float* mask = (const float*)d_in[1];   // (1,32,64,128) fp32, values {0,1}
    const float* proj = (const float*)d_in[2];   // (256,128) fp32
    int* out = (int*)d_out;                      // 8388608 inlier + 4194304 outlier int32

    const size_t tp_bytes = (size_t)DIM_D * DIM_S * sizeof(float);   // 128 KB
    if (ws_size >= tp_bytes) {
        float* projT = (float*)d_ws;
        transpose_proj_kernel<<<DIM_D, DIM_S, 0, stream>>>(proj, projT);
        qjl_sketch_kernel<true><<<NB_HG, 256, 0, stream>>>(data, mask, projT, out);
    } else {
        qjl_sketch_kernel<false><<<NB_HG, 256, 0, stream>>>(data, mask, proj, out);
    }
}